// Round 3
// baseline (2284.394 us; speedup 1.0000x reference)
//
#include <hip/hip_runtime.h>

// VQ-VAE vector quantizer step on MI355X (gfx950).
// Round 3: distance argmin via split-bf16 MFMA (z = z_hi + z_lo in bf16;
// dot = z_hi.e_hi + z_hi.e_lo + z_lo.e_hi as one virtual-K=768 bf16 GEMM),
// per-block top-2 per token, then exact-f32 rescore replicating round-1
// arithmetic bit-for-bit (which passed with zero index flips).
// Also: parallel scan replaces the serial single-thread scan.

#define NT 131072   // tokens
#define NE 1024     // codebook entries
#define ED 256      // embedding dim

// Output layout (flat f32, reference return order)
static const size_t OFF_QL   = 0;            // quant_loss (1)
static const size_t OFF_CL   = 1;            // commit_loss (1)
static const size_t OFF_ZQ   = 2;            // z_q_st (131072*256)
static const size_t OFF_PPL  = 33554434ULL;  // perplexity (1)
static const size_t OFF_OH   = 33554435ULL;  // min_encodings (131072*1024)
static const size_t OFF_IDX  = 167772163ULL; // idx (131072)
static const size_t OFF_NEMB = 167903235ULL; // new_emb_weight (1024*256)
static const size_t OFF_NN   = 168165379ULL; // new_n_mat (1024)
static const size_t OFF_NM   = 168166403ULL; // new_m_mat (1024*256)

typedef __attribute__((ext_vector_type(8))) short short8;
typedef __attribute__((ext_vector_type(4))) float floatx4;

__device__ inline void gl2lds16(const void* g, void* l) {
  __builtin_amdgcn_global_load_lds(
      (const __attribute__((address_space(1))) unsigned int*)g,
      (__attribute__((address_space(3))) unsigned int*)l, 16, 0, 0);
}

__device__ inline void top2_ins(float sv, int ci, float& v0, int& i0,
                                float& v1, int& i1) {
  if (sv < v0 || (sv == v0 && ci < i0)) { v1 = v0; i1 = i0; v0 = sv; i0 = ci; }
  else if (sv < v1 || (sv == v1 && ci < i1)) { v1 = sv; i1 = ci; }
}

// ---------------------------------------------------------------- row norms
// (kept: rescore path replicates round-1 arithmetic, which used these)
__global__ __launch_bounds__(256) void rownorm_k(const float* __restrict__ x,
                                                 float* __restrict__ o, int nrows) {
  int wid  = blockIdx.x * 4 + (threadIdx.x >> 6);  // one wave per row
  int lane = threadIdx.x & 63;
  if (wid >= nrows) return;
  float4 v = ((const float4*)(x + (size_t)wid * ED))[lane];
  float s = v.x * v.x + v.y * v.y + v.z * v.z + v.w * v.w;
  #pragma unroll
  for (int off = 32; off; off >>= 1) s += __shfl_down(s, off, 64);
  if (lane == 0) o[wid] = s;
}

// ----------------------------------------------- f32 -> (bf16 hi, bf16 lo)
__device__ inline unsigned short f2bf_rne(float f) {
  unsigned int u = __float_as_uint(f);
  u += 0x7fffu + ((u >> 16) & 1u);
  return (unsigned short)(u >> 16);
}
__device__ inline float bf2f(unsigned short b) {
  return __uint_as_float(((unsigned int)b) << 16);
}

__global__ __launch_bounds__(256) void cvt_k(const float* __restrict__ x,
                                             unsigned short* __restrict__ hi,
                                             unsigned short* __restrict__ lo,
                                             int n4) {
  int i = blockIdx.x * 256 + threadIdx.x;
  if (i >= n4) return;
  float4 v = ((const float4*)x)[i];
  ushort4 h, l;
  h.x = f2bf_rne(v.x); l.x = f2bf_rne(v.x - bf2f(h.x));
  h.y = f2bf_rne(v.y); l.y = f2bf_rne(v.y - bf2f(h.y));
  h.z = f2bf_rne(v.z); l.z = f2bf_rne(v.z - bf2f(h.z));
  h.w = f2bf_rne(v.w); l.w = f2bf_rne(v.w - bf2f(h.w));
  ((ushort4*)hi)[i] = h;
  ((ushort4*)lo)[i] = l;
}

// --------------------------------------- MFMA distance GEMM, top-2 per row
// Block 256 = 4 waves, tile 128 tokens x 128 codes, virtual K = 768:
// seg0: z_hi.e_hi, seg1: z_hi.e_lo, seg2: z_lo.e_hi.
// XCD swizzle: all 8 code-tiles of a token-block on one XCD (A stays in L2).
__global__ __launch_bounds__(256) void mfma_argmin_k(
    const unsigned short* __restrict__ zhi, const unsigned short* __restrict__ zlo,
    const unsigned short* __restrict__ ehi, const unsigned short* __restrict__ elo,
    const float* __restrict__ enorm, float4* __restrict__ gws) {
  __shared__ unsigned short As[128 * 32];   // 8 KB, row-major [row][k]
  __shared__ unsigned short Bs[128 * 32];   // 8 KB
  __shared__ float4 sm_top[128][2];         // 4 KB epilogue

  const int b = blockIdx.x;
  const int xcd = b & 7;
  const int t = b >> 3;
  const int ct = t & 7;
  const int row_blk = (t >> 3) + (xcd << 7);
  const int row0 = row_blk * 128;
  const int col0 = ct * 128;

  const int tid = threadIdx.x;
  const int lane = tid & 63, w = tid >> 6;
  const int wr = w >> 1, wc = w & 1;        // wave tile: 64x64
  const int m16 = lane & 15, q = lane >> 4;

  // staging map: flat chunk f covers (row = f>>2, kchunk = f&3), 16 B each
  const int r1 = tid >> 2, c1 = (tid & 3) * 8;

  floatx4 acc[4][4];
  #pragma unroll
  for (int i = 0; i < 4; i++)
    #pragma unroll
    for (int j = 0; j < 4; j++) acc[i][j] = (floatx4){0.f, 0.f, 0.f, 0.f};

  for (int s = 0; s < 24; ++s) {
    const int seg = s >> 3;
    const int ks = (s & 7) * 32;
    const unsigned short* Aseg = (seg < 2) ? zhi : zlo;
    const unsigned short* Bseg = (seg == 1) ? elo : ehi;

    gl2lds16(Aseg + (size_t)(row0 + r1) * ED + ks + c1,      As + tid * 8);
    gl2lds16(Aseg + (size_t)(row0 + r1 + 64) * ED + ks + c1, As + (tid + 256) * 8);
    gl2lds16(Bseg + (size_t)(col0 + r1) * ED + ks + c1,      Bs + tid * 8);
    gl2lds16(Bseg + (size_t)(col0 + r1 + 64) * ED + ks + c1, Bs + (tid + 256) * 8);
    __syncthreads();   // compiler emits vmcnt(0) drain before barrier

    short8 a[4], bfr[4];
    #pragma unroll
    for (int fi = 0; fi < 4; fi++)
      a[fi] = *(const short8*)(As + (wr * 64 + fi * 16 + m16) * 32 + q * 8);
    #pragma unroll
    for (int fj = 0; fj < 4; fj++)
      bfr[fj] = *(const short8*)(Bs + (wc * 64 + fj * 16 + m16) * 32 + q * 8);

    #pragma unroll
    for (int fi = 0; fi < 4; fi++)
      #pragma unroll
      for (int fj = 0; fj < 4; fj++)
        acc[fi][fj] = __builtin_amdgcn_mfma_f32_16x16x32_bf16(
            a[fi], bfr[fj], acc[fi][fj], 0, 0, 0);
    __syncthreads();   // protect LDS before next stage
  }

  // ---- epilogue: s = en[col] - 2*dot; top-2 per row over this 128-col slab
  float enl[4];
  #pragma unroll
  for (int fj = 0; fj < 4; fj++)
    enl[fj] = enorm[col0 + wc * 64 + fj * 16 + m16];

  #pragma unroll
  for (int fi = 0; fi < 4; fi++) {
    #pragma unroll
    for (int reg = 0; reg < 4; reg++) {
      float v0 = 3.4e38f, v1 = 3.4e38f;
      int   i0 = 0x7fffffff, i1 = 0x7fffffff;
      #pragma unroll
      for (int fj = 0; fj < 4; fj++) {
        float sv = enl[fj] - 2.0f * acc[fi][fj][reg];
        int   ci = col0 + wc * 64 + fj * 16 + m16;
        top2_ins(sv, ci, v0, i0, v1, i1);
      }
      // reduce across the 16 lanes sharing this row (same q)
      #pragma unroll
      for (int msk = 1; msk < 16; msk <<= 1) {
        float ov0 = __shfl_xor(v0, msk, 64); int oi0 = __shfl_xor(i0, msk, 64);
        float ov1 = __shfl_xor(v1, msk, 64); int oi1 = __shfl_xor(i1, msk, 64);
        top2_ins(ov0, oi0, v0, i0, v1, i1);
        top2_ins(ov1, oi1, v0, i0, v1, i1);
      }
      if (m16 == 0)
        sm_top[wr * 64 + fi * 16 + q * 4 + reg][wc] =
            make_float4(v0, __int_as_float(i0), v1, __int_as_float(i1));
    }
  }
  __syncthreads();
  if (tid < 128) {
    float4 A0 = sm_top[tid][0], B0 = sm_top[tid][1];
    float v0 = A0.x, v1 = A0.z;
    int   i0 = __float_as_int(A0.y), i1 = __float_as_int(A0.w);
    top2_ins(B0.x, __float_as_int(B0.y), v0, i0, v1, i1);
    top2_ins(B0.z, __float_as_int(B0.w), v0, i0, v1, i1);
    gws[(size_t)(row0 + tid) * 8 + ct] =
        make_float4(v0, __int_as_float(i0), v1, __int_as_float(i1));
  }
}

// --------------------- combine 8 slabs' top-2, exact-f32 rescore (round-1 ops)
__global__ __launch_bounds__(256) void rescore_k(
    const float* __restrict__ z, const float* __restrict__ emb,
    const float4* __restrict__ gws, const float* __restrict__ znorm,
    const float* __restrict__ enorm, int* __restrict__ idxw) {
  const int tid = threadIdx.x;
  const int tok = blockIdx.x * 128 + (tid >> 1);
  const int cand = tid & 1;

  float v0 = 3.4e38f, v1 = 3.4e38f;
  int   i0 = 0x7fffffff, i1 = 0x7fffffff;
  #pragma unroll
  for (int c = 0; c < 8; c++) {
    float4 e = gws[(size_t)tok * 8 + c];
    top2_ins(e.x, __float_as_int(e.y), v0, i0, v1, i1);
    top2_ins(e.z, __float_as_int(e.w), v0, i0, v1, i1);
  }
  const int ci = cand ? i1 : i0;

  // exact f32 dot, k ascending, acc += a*b — identical to round-1 kernel
  const float4* zr = (const float4*)(z + (size_t)tok * ED);
  const float4* er = (const float4*)(emb + (size_t)ci * ED);
  float acc = 0.f;
  for (int c4 = 0; c4 < 64; c4++) {
    float4 av = zr[c4], bv = er[c4];
    acc += av.x * bv.x; acc += av.y * bv.y;
    acc += av.z * bv.z; acc += av.w * bv.w;
  }
  float s = znorm[tok] + enorm[ci];   // same absorption as numpy's d
  float d = s - 2.0f * acc;

  float od = __shfl_xor(d, 1, 64);
  int   oc = __shfl_xor(ci, 1, 64);
  if (cand == 0) {
    int best = (od < d || (od == d && oc < ci)) ? oc : ci;
    idxw[tok] = best;
  }
}

// ------------------------- streaming per-token outputs: z_q, one-hot, idx, loss
__global__ __launch_bounds__(256) void zq_oh_k(
    const float* __restrict__ z, const float* __restrict__ emb,
    const int* __restrict__ idxw, float* __restrict__ out,
    double* __restrict__ lossacc) {
  const int t = threadIdx.x;
  const int tl = t >> 6, lane = t & 63;
  const int tok = blockIdx.x * 4 + tl;
  const int id = idxw[tok];

  float4 z4 = ((const float4*)(z   + (size_t)tok * ED))[lane];
  float4 e4 = ((const float4*)(emb + (size_t)id  * ED))[lane];
  float4 qv;
  qv.x = z4.x + (e4.x - z4.x);
  qv.y = z4.y + (e4.y - z4.y);
  qv.z = z4.z + (e4.z - z4.z);
  qv.w = z4.w + (e4.w - z4.w);
  ((float4*)(out + OFF_ZQ + (size_t)tok * ED))[lane] = qv;

  float dx = e4.x - z4.x, dy = e4.y - z4.y, dz = e4.z - z4.z, dw = e4.w - z4.w;
  double lsum = (double)(dx * dx) + (double)(dy * dy)
              + (double)(dz * dz) + (double)(dw * dw);

  float* ohb = out + OFF_OH + (size_t)tok * NE;
  #pragma unroll
  for (int it = 0; it < 4; ++it) {
    int f4i = it * 64 + lane;
    int c0 = f4i * 4;
    float4 v;
    v.x = (c0 + 0 == id) ? 1.0f : 0.0f;
    v.y = (c0 + 1 == id) ? 1.0f : 0.0f;
    v.z = (c0 + 2 == id) ? 1.0f : 0.0f;
    v.w = (c0 + 3 == id) ? 1.0f : 0.0f;
    ((float4*)ohb)[f4i] = v;
  }
  if (lane == 0) out[OFF_IDX + tok] = (float)id;

  #pragma unroll
  for (int off = 32; off; off >>= 1) lsum += __shfl_down(lsum, off, 64);
  __shared__ double lred[4];
  if (lane == 0) lred[tl] = lsum;
  __syncthreads();
  if (t == 0)
    unsafeAtomicAdd(&lossacc[blockIdx.x & 255],
                    lred[0] + lred[1] + lred[2] + lred[3]);
}

// ------------------------------------------------ histogram (LDS-privatized)
__global__ __launch_bounds__(256) void hist_k(const int* __restrict__ idxw,
                                              int* __restrict__ counts) {
  __shared__ int lc[NE];
  for (int i = threadIdx.x; i < NE; i += 256) lc[i] = 0;
  __syncthreads();
  const int stride = gridDim.x * 256;
  for (int i = blockIdx.x * 256 + threadIdx.x; i < NT; i += stride)
    atomicAdd(&lc[idxw[i]], 1);
  __syncthreads();
  for (int i = threadIdx.x; i < NE; i += 256) {
    int v = lc[i];
    if (v) atomicAdd(&counts[i], v);
  }
}

// ------------------------------------------ parallel exclusive prefix sum
__global__ __launch_bounds__(256) void scan_k(const int* __restrict__ counts,
                                              int* __restrict__ offsets) {
  __shared__ int wtot[4], wpre[4];
  const int tid = threadIdx.x, lane = tid & 63, w = tid >> 6;
  int4 v = ((const int4*)counts)[tid];
  int tsum = v.x + v.y + v.z + v.w;
  int x = tsum;
  #pragma unroll
  for (int off = 1; off < 64; off <<= 1) {
    int y = __shfl_up(x, off, 64);
    if (lane >= off) x += y;
  }
  if (lane == 63) wtot[w] = x;
  __syncthreads();
  if (tid == 0) { int s = 0; for (int i = 0; i < 4; i++) { wpre[i] = s; s += wtot[i]; } }
  __syncthreads();
  int excl = wpre[w] + x - tsum;
  int4 o; o.x = excl; o.y = excl + v.x; o.z = o.y + v.y; o.w = o.z + v.z;
  ((int4*)offsets)[tid] = o;
}

// -------------------------------------------------- scatter tokens into buckets
__global__ __launch_bounds__(256) void scatter_k(
    const int* __restrict__ idxw, const int* __restrict__ offsets,
    int* __restrict__ cursor, int* __restrict__ bucket) {
  int i = blockIdx.x * 256 + threadIdx.x;
  int id = idxw[i];
  int pos = atomicAdd(&cursor[id], 1);
  bucket[offsets[id] + pos] = i;
}

// ------------------- per-code segment sum (no atomics) fused with EMA update
__global__ __launch_bounds__(256) void segsum_k(
    const float* __restrict__ z, const float* __restrict__ nmat,
    const float* __restrict__ mmat, const int* __restrict__ counts,
    const int* __restrict__ offsets, const int* __restrict__ bucket,
    float* __restrict__ out) {
  const int j = blockIdx.x, t = threadIdx.x;
  const int cnt = counts[j], off = offsets[j];
  float s = 0.f;
  int i = 0;
  for (; i + 4 <= cnt; i += 4) {
    int t0 = bucket[off + i + 0], t1 = bucket[off + i + 1];
    int t2 = bucket[off + i + 2], t3 = bucket[off + i + 3];
    float a = z[(size_t)t0 * ED + t];
    float b = z[(size_t)t1 * ED + t];
    float c = z[(size_t)t2 * ED + t];
    float d = z[(size_t)t3 * ED + t];
    s += a; s += b; s += c; s += d;
  }
  for (; i < cnt; ++i) s += z[(size_t)bucket[off + i] * ED + t];

  float newn = nmat[j] * 0.99f + (float)cnt * 0.01f;
  if (t == 0) out[OFF_NN + j] = newn;
  const size_t o = (size_t)j * ED + t;
  float newm = 0.99f * mmat[o] + 0.01f * s;
  out[OFF_NM + o]   = newm;
  out[OFF_NEMB + o] = newm / newn;
}

// ------------------------------------------------------- scalar finalizers
__global__ __launch_bounds__(256) void scalars_k(
    const double* __restrict__ lossacc, const int* __restrict__ counts,
    float* __restrict__ out) {
  const int t = threadIdx.x;
  double lsum = lossacc[t];
  double h = 0.0;
  for (int c = t; c < NE; c += 256) {
    double e = (double)counts[c] / (double)NT;
    h += e * log(e + 1e-10);
  }
  #pragma unroll
  for (int off = 32; off; off >>= 1) {
    lsum += __shfl_down(lsum, off, 64);
    h    += __shfl_down(h,    off, 64);
  }
  __shared__ double sl[4], sh[4];
  if ((t & 63) == 0) { sl[t >> 6] = lsum; sh[t >> 6] = h; }
  __syncthreads();
  if (t == 0) {
    double mean = (sl[0] + sl[1] + sl[2] + sl[3]) / (double)((size_t)NT * ED);
    out[OFF_QL]  = (float)mean;
    out[OFF_CL]  = (float)(0.25 * mean);
    out[OFF_PPL] = (float)exp(-(sh[0] + sh[1] + sh[2] + sh[3]));
  }
}

// ------------------------------------------------------------------ launch
extern "C" void kernel_launch(void* const* d_in, const int* in_sizes, int n_in,
                              void* d_out, int out_size, void* d_ws, size_t ws_size,
                              hipStream_t stream) {
  const float* z    = (const float*)d_in[0];
  const float* emb  = (const float*)d_in[1];
  const float* nmat = (const float*)d_in[2];
  const float* mmat = (const float*)d_in[3];
  float* out = (float*)d_out;
  char*  ws  = (char*)d_ws;

  // ws layout (byte offsets):
  //   0        lossacc  double[256]       (pad to 4096)
  //   4096     counts   int[1024]
  //   8192     cursor   int[1024]
  //   12288    offsets  int[1024]
  //   16384    bucket   int[NT]           512 KB
  //   540672   idxw     int[NT]           512 KB
  //   1064960  znorm    float[NT]         512 KB
  //   1589248  enorm    float[1024]       4 KB
  //   1593344  ehi      bf16[NE*ED]       512 KB
  //   2117632  elo      bf16[NE*ED]       512 KB
  //   2641920  gws      float4[NT*8]      16 MB
  //   19419136 zhi      bf16[NT*ED]       64 MB
  //   86528000 zlo      bf16[NT*ED]       64 MB   (total ~147 MB)
  double*         lossacc = (double*)ws;
  int*            counts  = (int*)(ws + 4096);
  int*            cursor  = (int*)(ws + 8192);
  int*            offsets = (int*)(ws + 12288);
  int*            bucket  = (int*)(ws + 16384);
  int*            idxw    = (int*)(ws + 540672);
  float*          znorm   = (float*)(ws + 1064960);
  float*          enorm   = (float*)(ws + 1589248);
  unsigned short* ehi     = (unsigned short*)(ws + 1593344);
  unsigned short* elo     = (unsigned short*)(ws + 2117632);
  float4*         gws     = (float4*)(ws + 2641920);
  unsigned short* zhi     = (unsigned short*)(ws + 19419136);
  unsigned short* zlo     = (unsigned short*)(ws + 86528000);

  hipMemsetAsync(ws, 0, 12288, stream);  // lossacc + counts + cursor

  hipLaunchKernelGGL(rownorm_k, dim3(NT / 4), dim3(256), 0, stream, z, znorm, NT);
  hipLaunchKernelGGL(rownorm_k, dim3(NE / 4), dim3(256), 0, stream, emb, enorm, NE);
  hipLaunchKernelGGL(cvt_k, dim3(NT * ED / 4 / 256), dim3(256), 0, stream,
                     z, zhi, zlo, NT * ED / 4);
  hipLaunchKernelGGL(cvt_k, dim3(NE * ED / 4 / 256), dim3(256), 0, stream,
                     emb, ehi, elo, NE * ED / 4);
  hipLaunchKernelGGL(mfma_argmin_k, dim3(NT / 128 * 8), dim3(256), 0, stream,
                     zhi, zlo, ehi, elo, enorm, gws);
  hipLaunchKernelGGL(rescore_k, dim3(NT / 128), dim3(256), 0, stream,
                     z, emb, gws, znorm, enorm, idxw);
  hipLaunchKernelGGL(zq_oh_k, dim3(NT / 4), dim3(256), 0, stream,
                     z, emb, idxw, out, lossacc);
  hipLaunchKernelGGL(hist_k, dim3(64), dim3(256), 0, stream, idxw, counts);
  hipLaunchKernelGGL(scan_k, dim3(1), dim3(256), 0, stream, counts, offsets);
  hipLaunchKernelGGL(scatter_k, dim3(NT / 256), dim3(256), 0, stream,
                     idxw, offsets, cursor, bucket);
  hipLaunchKernelGGL(segsum_k, dim3(NE), dim3(256), 0, stream,
                     z, nmat, mmat, counts, offsets, bucket, out);
  hipLaunchKernelGGL(scalars_k, dim3(1), dim3(256), 0, stream,
                     lossacc, counts, out);
}